// Round 1
// baseline (3140.495 us; speedup 1.0000x reference)
//
#include <hip/hip_runtime.h>
#include <math.h>

// Problem: LinearAttention  N=4, S=8192, D_IN=1024, ATTN_DIM=1024, OUT_DIM=1024
// Phase A: Q/K/V GEMMs fused (shared x tile), elu+1 on Q/K, KV & Ksum reductions
//          via LDS partial + atomicAdd.  Q (post-feature-map) -> workspace.
// Phase B: out = gelu( V' @ wo + bo ),  V' built on-the-fly from Q, KV, Ksum.

#define N_B   4
#define S_LEN 8192
#define D_INN 1024
#define H_DIM 1024
#define O_DIM 1024
#define M_TOT (N_B * S_LEN)   // 32768

__device__ __forceinline__ float elu1(float v) {
    // elu(v) + 1 :  v>0 ? v+1 : exp(v)
    return v > 0.0f ? v + 1.0f : __expf(v);
}

__device__ __forceinline__ float gelu_tanh(float v) {
    float u = 0.7978845608028654f * (v + 0.044715f * v * v * v);
    return 0.5f * v * (1.0f + tanhf(u));
}

// ---------------------------------------------------------------------------
// Phase A: 128x64 output tile per block, 256 threads, 8x4 microtile.
// Computes Q,K,V tiles simultaneously from one staged x tile.
// ---------------------------------------------------------------------------
__global__ __launch_bounds__(256) void qkv_fused(
    const float* __restrict__ x,
    const float* __restrict__ wq, const float* __restrict__ bq,
    const float* __restrict__ wk, const float* __restrict__ bk,
    const float* __restrict__ wv, const float* __restrict__ bv,
    float* __restrict__ Qout, float* __restrict__ KV, float* __restrict__ Ks)
{
    __shared__ float As[16][132];   // x tile, transposed [k][m], padded
    __shared__ float Bq[16][68];
    __shared__ float Bk[16][68];
    __shared__ float Bv[16][68];
    __shared__ float red[16][64];

    const int t  = threadIdx.x;
    const int m0 = blockIdx.x * 128;
    const int h0 = blockIdx.y * 64;
    const int n  = m0 / S_LEN;      // tile never crosses batch boundary (8192 % 128 == 0)

    const int hc = t & 15;          // col group -> cols h0 + hc*4 .. +3
    const int mr = t >> 4;          // row group -> rows m0 + mr*8 .. +7

    const int a_r = t >> 2;         // 0..63 (x staging row; +64 for second row)
    const int a_c = (t & 3) * 4;    // 0,4,8,12
    const int w_r = t >> 4;         // 0..15 (w staging row)
    const int w_c = (t & 15) * 4;   // 0..60

    float accq[8][4], acck[8][4], accv[8][4];
    #pragma unroll
    for (int i = 0; i < 8; ++i)
        #pragma unroll
        for (int j = 0; j < 4; ++j) { accq[i][j] = 0.f; acck[i][j] = 0.f; accv[i][j] = 0.f; }

    for (int k0 = 0; k0 < D_INN; k0 += 16) {
        float4 xa = *(const float4*)&x[(size_t)(m0 + a_r)      * D_INN + k0 + a_c];
        float4 xb = *(const float4*)&x[(size_t)(m0 + a_r + 64) * D_INN + k0 + a_c];
        As[a_c + 0][a_r] = xa.x; As[a_c + 1][a_r] = xa.y;
        As[a_c + 2][a_r] = xa.z; As[a_c + 3][a_r] = xa.w;
        As[a_c + 0][a_r + 64] = xb.x; As[a_c + 1][a_r + 64] = xb.y;
        As[a_c + 2][a_r + 64] = xb.z; As[a_c + 3][a_r + 64] = xb.w;
        *(float4*)&Bq[w_r][w_c] = *(const float4*)&wq[(size_t)(k0 + w_r) * H_DIM + h0 + w_c];
        *(float4*)&Bk[w_r][w_c] = *(const float4*)&wk[(size_t)(k0 + w_r) * H_DIM + h0 + w_c];
        *(float4*)&Bv[w_r][w_c] = *(const float4*)&wv[(size_t)(k0 + w_r) * H_DIM + h0 + w_c];
        __syncthreads();

        #pragma unroll
        for (int k = 0; k < 16; ++k) {
            float4 a0 = *(const float4*)&As[k][mr * 8];
            float4 a1 = *(const float4*)&As[k][mr * 8 + 4];
            float4 b0 = *(const float4*)&Bq[k][hc * 4];
            float4 b1 = *(const float4*)&Bk[k][hc * 4];
            float4 b2 = *(const float4*)&Bv[k][hc * 4];
            float a[8] = {a0.x, a0.y, a0.z, a0.w, a1.x, a1.y, a1.z, a1.w};
            float q[4] = {b0.x, b0.y, b0.z, b0.w};
            float kk[4] = {b1.x, b1.y, b1.z, b1.w};
            float vv[4] = {b2.x, b2.y, b2.z, b2.w};
            #pragma unroll
            for (int i = 0; i < 8; ++i)
                #pragma unroll
                for (int j = 0; j < 4; ++j) {
                    accq[i][j] = fmaf(a[i], q[j],  accq[i][j]);
                    acck[i][j] = fmaf(a[i], kk[j], acck[i][j]);
                    accv[i][j] = fmaf(a[i], vv[j], accv[i][j]);
                }
        }
        __syncthreads();
    }

    // epilogue: bias, elu+1 on Q/K, Q store, KV/Ksum partial reduce
    float4 bqv = *(const float4*)&bq[h0 + hc * 4];
    float4 bkv = *(const float4*)&bk[h0 + hc * 4];
    float4 bvv = *(const float4*)&bv[h0 + hc * 4];
    float kvp[4] = {0.f, 0.f, 0.f, 0.f};
    float ksp[4] = {0.f, 0.f, 0.f, 0.f};
    #pragma unroll
    for (int i = 0; i < 8; ++i) {
        const int row = m0 + mr * 8 + i;
        float4 qv;
        qv.x = elu1(accq[i][0] + bqv.x);
        qv.y = elu1(accq[i][1] + bqv.y);
        qv.z = elu1(accq[i][2] + bqv.z);
        qv.w = elu1(accq[i][3] + bqv.w);
        *(float4*)&Qout[(size_t)row * H_DIM + h0 + hc * 4] = qv;

        float k0e = elu1(acck[i][0] + bkv.x);
        float k1e = elu1(acck[i][1] + bkv.y);
        float k2e = elu1(acck[i][2] + bkv.z);
        float k3e = elu1(acck[i][3] + bkv.w);
        float v0e = accv[i][0] + bvv.x;
        float v1e = accv[i][1] + bvv.y;
        float v2e = accv[i][2] + bvv.z;
        float v3e = accv[i][3] + bvv.w;
        kvp[0] = fmaf(k0e, v0e, kvp[0]); ksp[0] += k0e;
        kvp[1] = fmaf(k1e, v1e, kvp[1]); ksp[1] += k1e;
        kvp[2] = fmaf(k2e, v2e, kvp[2]); ksp[2] += k2e;
        kvp[3] = fmaf(k3e, v3e, kvp[3]); ksp[3] += k3e;
    }
    *(float4*)&red[mr][hc * 4] = make_float4(kvp[0], kvp[1], kvp[2], kvp[3]);
    __syncthreads();
    if (t < 64) {
        float s = 0.f;
        #pragma unroll
        for (int r = 0; r < 16; ++r) s += red[r][t];
        atomicAdd(&KV[n * H_DIM + h0 + t], s);
    }
    __syncthreads();
    *(float4*)&red[mr][hc * 4] = make_float4(ksp[0], ksp[1], ksp[2], ksp[3]);
    __syncthreads();
    if (t < 64) {
        float s = 0.f;
        #pragma unroll
        for (int r = 0; r < 16; ++r) s += red[r][t];
        atomicAdd(&Ks[n * H_DIM + h0 + t], s);
    }
}

// ---------------------------------------------------------------------------
// Phase B: out = gelu( V' @ wo + bo ),  V'[m,k] = q*KV[n,k] / (q*Ksum[n,k]+1e-6)
// ---------------------------------------------------------------------------
__global__ __launch_bounds__(256) void out_gemm(
    const float* __restrict__ Q, const float* __restrict__ KV,
    const float* __restrict__ Ks,
    const float* __restrict__ wo, const float* __restrict__ bo,
    float* __restrict__ out)
{
    __shared__ float As[16][132];
    __shared__ float Bs[16][68];

    const int t  = threadIdx.x;
    const int m0 = blockIdx.x * 128;
    const int h0 = blockIdx.y * 64;
    const int n  = m0 / S_LEN;

    const int hc = t & 15;
    const int mr = t >> 4;
    const int a_r = t >> 2;
    const int a_c = (t & 3) * 4;
    const int w_r = t >> 4;
    const int w_c = (t & 15) * 4;

    float acc[8][4];
    #pragma unroll
    for (int i = 0; i < 8; ++i)
        #pragma unroll
        for (int j = 0; j < 4; ++j) acc[i][j] = 0.f;

    for (int k0 = 0; k0 < H_DIM; k0 += 16) {
        float4 kv4 = *(const float4*)&KV[n * H_DIM + k0 + a_c];
        float4 ks4 = *(const float4*)&Ks[n * H_DIM + k0 + a_c];
        float4 q0  = *(const float4*)&Q[(size_t)(m0 + a_r)      * H_DIM + k0 + a_c];
        float4 q1  = *(const float4*)&Q[(size_t)(m0 + a_r + 64) * H_DIM + k0 + a_c];
        As[a_c + 0][a_r] = q0.x * kv4.x * __builtin_amdgcn_rcpf(fmaf(q0.x, ks4.x, 1e-6f));
        As[a_c + 1][a_r] = q0.y * kv4.y * __builtin_amdgcn_rcpf(fmaf(q0.y, ks4.y, 1e-6f));
        As[a_c + 2][a_r] = q0.z * kv4.z * __builtin_amdgcn_rcpf(fmaf(q0.z, ks4.z, 1e-6f));
        As[a_c + 3][a_r] = q0.w * kv4.w * __builtin_amdgcn_rcpf(fmaf(q0.w, ks4.w, 1e-6f));
        As[a_c + 0][a_r + 64] = q1.x * kv4.x * __builtin_amdgcn_rcpf(fmaf(q1.x, ks4.x, 1e-6f));
        As[a_c + 1][a_r + 64] = q1.y * kv4.y * __builtin_amdgcn_rcpf(fmaf(q1.y, ks4.y, 1e-6f));
        As[a_c + 2][a_r + 64] = q1.z * kv4.z * __builtin_amdgcn_rcpf(fmaf(q1.z, ks4.z, 1e-6f));
        As[a_c + 3][a_r + 64] = q1.w * kv4.w * __builtin_amdgcn_rcpf(fmaf(q1.w, ks4.w, 1e-6f));
        *(float4*)&Bs[w_r][w_c] = *(const float4*)&wo[(size_t)(k0 + w_r) * O_DIM + h0 + w_c];
        __syncthreads();

        #pragma unroll
        for (int k = 0; k < 16; ++k) {
            float4 a0 = *(const float4*)&As[k][mr * 8];
            float4 a1 = *(const float4*)&As[k][mr * 8 + 4];
            float4 b0 = *(const float4*)&Bs[k][hc * 4];
            float a[8] = {a0.x, a0.y, a0.z, a0.w, a1.x, a1.y, a1.z, a1.w};
            float b[4] = {b0.x, b0.y, b0.z, b0.w};
            #pragma unroll
            for (int i = 0; i < 8; ++i)
                #pragma unroll
                for (int j = 0; j < 4; ++j)
                    acc[i][j] = fmaf(a[i], b[j], acc[i][j]);
        }
        __syncthreads();
    }

    float4 bov = *(const float4*)&bo[h0 + hc * 4];
    #pragma unroll
    for (int i = 0; i < 8; ++i) {
        const int row = m0 + mr * 8 + i;
        float4 o;
        o.x = gelu_tanh(acc[i][0] + bov.x);
        o.y = gelu_tanh(acc[i][1] + bov.y);
        o.z = gelu_tanh(acc[i][2] + bov.z);
        o.w = gelu_tanh(acc[i][3] + bov.w);
        *(float4*)&out[(size_t)row * O_DIM + h0 + hc * 4] = o;
    }
}

extern "C" void kernel_launch(void* const* d_in, const int* in_sizes, int n_in,
                              void* d_out, int out_size, void* d_ws, size_t ws_size,
                              hipStream_t stream)
{
    const float* x  = (const float*)d_in[0];
    const float* wq = (const float*)d_in[1];
    const float* bq = (const float*)d_in[2];
    const float* wk = (const float*)d_in[3];
    const float* bk = (const float*)d_in[4];
    const float* wv = (const float*)d_in[5];
    const float* bv = (const float*)d_in[6];
    const float* wo = (const float*)d_in[7];
    const float* bo = (const float*)d_in[8];
    float* out = (float*)d_out;

    // workspace layout: Q (elu+1 applied) fp32 [32768,1024], then KV, Ksum [4,1024]
    float* Qws = (float*)d_ws;
    float* KV  = Qws + (size_t)M_TOT * H_DIM;
    float* Ks  = KV + N_B * H_DIM;

    hipMemsetAsync(KV, 0, 2 * N_B * H_DIM * sizeof(float), stream);

    dim3 gridA(M_TOT / 128, H_DIM / 64);
    qkv_fused<<<gridA, dim3(256), 0, stream>>>(x, wq, bq, wk, bk, wv, bv, Qws, KV, Ks);

    dim3 gridB(M_TOT / 128, O_DIM / 64);
    out_gemm<<<gridB, dim3(256), 0, stream>>>(Qws, KV, Ks, wo, bo, out);
}

// Round 3
// 635.467 us; speedup vs baseline: 4.9420x; 4.9420x over previous
//
#include <hip/hip_runtime.h>
#include <math.h>
#include <stdint.h>

// LinearAttention  N=4, S=8192, D_IN=1024, ATTN_DIM=1024, OUT_DIM=1024
// bf16-MFMA pipeline:
//   wtrans x4 : w[k][n] fp32 -> wT[n][k] bf16   (MFMA frags need k-contiguous)
//   qkv_mfma  : Q/K/V GEMMs fused (shared x tile, fp32->bf16 in staging),
//               elu+1, Q->bf16 ws, KV/Ksum fp32 reduction via LDS + atomicAdd
//   vprime    : in-place Q <- Q*KV*rcp(Q*Ksum+1e-6)   (bf16 in/out, fp32 math)
//   out_mfma  : out = gelu(V' @ wo + bo)  fp32 store
//
// R2 bugfix: out_mfma LDS staging only covered k-cols 0..31 (half the tile);
// ks=1 MFMA read uninitialized LDS -> NaN. Staging now mirrors qkv_mfma's
// (coverage: A 256thr*2rep*16sh = 8192 = 128x64; B 256thr*2rep*8sh = 4096 = 64x64).

#define N_B   4
#define S_LEN 8192
#define M_TOT (N_B * S_LEN)   // 32768

typedef __attribute__((ext_vector_type(8))) __bf16 bf16x8;
typedef __attribute__((ext_vector_type(8))) unsigned short ushort8;
typedef __attribute__((ext_vector_type(4))) float f32x4;

__device__ __forceinline__ unsigned short f2bf(float f) {
    unsigned int u = __builtin_bit_cast(unsigned int, f);
    unsigned int r = (u + 0x7fffu + ((u >> 16) & 1u)) >> 16;   // RNE
    return (unsigned short)r;
}
__device__ __forceinline__ float bf2f(unsigned short s) {
    unsigned int u = ((unsigned int)s) << 16;
    return __builtin_bit_cast(float, u);
}
__device__ __forceinline__ float elu1(float v) { return v > 0.f ? v + 1.f : __expf(v); }
__device__ __forceinline__ float gelu_tanh(float v) {
    // gelu(v) = 0.5 v (1 + tanh(0.79788456 (v + 0.044715 v^3)))
    float u = 1.5957691216057308f * (v + 0.044715f * v * v * v);  // 2*c*(...)
    float e = __expf(u);                                          // tanh = 1 - 2/(e+1)
    float th = 1.f - 2.f / (e + 1.f);
    return 0.5f * v * (1.f + th);
}

// ---------------------------------------------------------------------------
// weight transpose + convert: w[k][n] fp32 (1024x1024) -> wT[n][k] bf16
// ---------------------------------------------------------------------------
__global__ __launch_bounds__(256) void wtrans(const float* __restrict__ w,
                                              unsigned short* __restrict__ wT)
{
    __shared__ float tile[64][65];
    const int t  = threadIdx.x;
    const int n0 = blockIdx.x * 64;
    const int k0 = blockIdx.y * 64;
    const int r  = t >> 2;
    const int c4 = (t & 3) * 16;
    #pragma unroll
    for (int j = 0; j < 4; ++j) {
        float4 v = *(const float4*)&w[(size_t)(k0 + r) * 1024 + n0 + c4 + j * 4];
        tile[r][c4 + j * 4 + 0] = v.x; tile[r][c4 + j * 4 + 1] = v.y;
        tile[r][c4 + j * 4 + 2] = v.z; tile[r][c4 + j * 4 + 3] = v.w;
    }
    __syncthreads();
    const int nn = t >> 2;
    const int kc = (t & 3) * 16;
    ushort8 o0, o1;
    #pragma unroll
    for (int j = 0; j < 8; ++j) o0[j] = f2bf(tile[kc + j][nn]);
    #pragma unroll
    for (int j = 0; j < 8; ++j) o1[j] = f2bf(tile[kc + 8 + j][nn]);
    *(ushort8*)&wT[(size_t)(n0 + nn) * 1024 + k0 + kc]     = o0;
    *(ushort8*)&wT[(size_t)(n0 + nn) * 1024 + k0 + kc + 8] = o1;
}

// ---------------------------------------------------------------------------
// Phase A: fused QKV.  BM=128, BN=64 (per matrix), BK=64, 4 waves (2x2),
// wave tile 64x32 per matrix = 4x2 tiles of 16x16, MFMA 16x16x32 bf16.
// ---------------------------------------------------------------------------
__global__ __launch_bounds__(256) void qkv_mfma(
    const float* __restrict__ x,
    const unsigned short* __restrict__ wqT,
    const unsigned short* __restrict__ wkT,
    const unsigned short* __restrict__ wvT,
    const float* __restrict__ bq, const float* __restrict__ bk,
    const float* __restrict__ bv,
    unsigned short* __restrict__ Qout,
    float* __restrict__ KV, float* __restrict__ Ks)
{
    __shared__ unsigned short Alds[128 * 72];     // rows padded 64->72 (+16B swizzle)
    __shared__ unsigned short Blds[3][64 * 72];
    __shared__ float redkv[8][64];
    __shared__ float redks[8][64];

    const int t  = threadIdx.x;
    const int h0 = blockIdx.x * 64;
    const int m0 = blockIdx.y * 128;
    const int n  = m0 >> 13;                      // m0 / 8192

    const int lane = t & 63, wid = t >> 6;
    const int wm = wid >> 1, wn = wid & 1;        // wave 2x2 over (M,N)
    const int lr = lane & 15, quad = lane >> 4;

    const int sr = t >> 2;                        // staging row 0..63
    const int sc = (t & 3) * 16;                  // x staging col group (16 floats)

    f32x4 accq[4][2], acck[4][2], accv[4][2];
    #pragma unroll
    for (int mi = 0; mi < 4; ++mi)
        #pragma unroll
        for (int nj = 0; nj < 2; ++nj) {
            accq[mi][nj] = (f32x4){0.f, 0.f, 0.f, 0.f};
            acck[mi][nj] = (f32x4){0.f, 0.f, 0.f, 0.f};
            accv[mi][nj] = (f32x4){0.f, 0.f, 0.f, 0.f};
        }

    for (int k0 = 0; k0 < 1024; k0 += 64) {
        // ---- global loads (before barrier: overlap previous compute) ----
        float4 xa[2][4];
        #pragma unroll
        for (int rep = 0; rep < 2; ++rep)
            #pragma unroll
            for (int j = 0; j < 4; ++j)
                xa[rep][j] = *(const float4*)&x[(size_t)(m0 + sr + 64 * rep) * 1024 + k0 + sc + 4 * j];
        ushort8 wq_r[2], wk_r[2], wv_r[2];
        #pragma unroll
        for (int rep = 0; rep < 2; ++rep) {
            const size_t off = (size_t)(h0 + sr) * 1024 + k0 + ((t & 3) + 4 * rep) * 8;
            wq_r[rep] = *(const ushort8*)&wqT[off];
            wk_r[rep] = *(const ushort8*)&wkT[off];
            wv_r[rep] = *(const ushort8*)&wvT[off];
        }
        __syncthreads();
        // ---- LDS stores ----
        #pragma unroll
        for (int rep = 0; rep < 2; ++rep) {
            float f[16] = {xa[rep][0].x, xa[rep][0].y, xa[rep][0].z, xa[rep][0].w,
                           xa[rep][1].x, xa[rep][1].y, xa[rep][1].z, xa[rep][1].w,
                           xa[rep][2].x, xa[rep][2].y, xa[rep][2].z, xa[rep][2].w,
                           xa[rep][3].x, xa[rep][3].y, xa[rep][3].z, xa[rep][3].w};
            ushort8 p0, p1;
            #pragma unroll
            for (int j = 0; j < 8; ++j) { p0[j] = f2bf(f[j]); p1[j] = f2bf(f[8 + j]); }
            *(ushort8*)&Alds[(sr + 64 * rep) * 72 + sc]     = p0;
            *(ushort8*)&Alds[(sr + 64 * rep) * 72 + sc + 8] = p1;
        }
        #pragma unroll
        for (int rep = 0; rep < 2; ++rep) {
            const int boff = sr * 72 + ((t & 3) + 4 * rep) * 8;
            *(ushort8*)&Blds[0][boff] = wq_r[rep];
            *(ushort8*)&Blds[1][boff] = wk_r[rep];
            *(ushort8*)&Blds[2][boff] = wv_r[rep];
        }
        __syncthreads();
        // ---- compute: 2 k-steps of 32 ----
        #pragma unroll
        for (int ks = 0; ks < 2; ++ks) {
            bf16x8 af[4];
            #pragma unroll
            for (int mi = 0; mi < 4; ++mi)
                af[mi] = __builtin_bit_cast(bf16x8,
                    *(const ushort8*)&Alds[(wm * 64 + mi * 16 + lr) * 72 + ks * 32 + quad * 8]);
            bf16x8 bfq[2], bfk[2], bfv[2];
            #pragma unroll
            for (int nj = 0; nj < 2; ++nj) {
                const int boff = (wn * 32 + nj * 16 + lr) * 72 + ks * 32 + quad * 8;
                bfq[nj] = __builtin_bit_cast(bf16x8, *(const ushort8*)&Blds[0][boff]);
                bfk[nj] = __builtin_bit_cast(bf16x8, *(const ushort8*)&Blds[1][boff]);
                bfv[nj] = __builtin_bit_cast(bf16x8, *(const ushort8*)&Blds[2][boff]);
            }
            #pragma unroll
            for (int mi = 0; mi < 4; ++mi)
                #pragma unroll
                for (int nj = 0; nj < 2; ++nj) {
                    accq[mi][nj] = __builtin_amdgcn_mfma_f32_16x16x32_bf16(af[mi], bfq[nj], accq[mi][nj], 0, 0, 0);
                    acck[mi][nj] = __builtin_amdgcn_mfma_f32_16x16x32_bf16(af[mi], bfk[nj], acck[mi][nj], 0, 0, 0);
                    accv[mi][nj] = __builtin_amdgcn_mfma_f32_16x16x32_bf16(af[mi], bfv[nj], accv[mi][nj], 0, 0, 0);
                }
        }
        __syncthreads();
    }

    // ---- epilogue: bias, elu+1, Q store (bf16), KV/Ksum partials ----
    float bqv[2], bkv[2], bvv[2];
    #pragma unroll
    for (int nj = 0; nj < 2; ++nj) {
        const int h = h0 + wn * 32 + nj * 16 + lr;
        bqv[nj] = bq[h]; bkv[nj] = bk[h]; bvv[nj] = bv[h];
    }
    float kvp[2] = {0.f, 0.f}, ksp[2] = {0.f, 0.f};
    #pragma unroll
    for (int mi = 0; mi < 4; ++mi)
        #pragma unroll
        for (int nj = 0; nj < 2; ++nj) {
            const int h = h0 + wn * 32 + nj * 16 + lr;
            #pragma unroll
            for (int r = 0; r < 4; ++r) {
                const int m = m0 + wm * 64 + mi * 16 + quad * 4 + r;
                float q = elu1(accq[mi][nj][r] + bqv[nj]);
                Qout[(size_t)m * 1024 + h] = f2bf(q);
                float kk = elu1(acck[mi][nj][r] + bkv[nj]);
                float vv = accv[mi][nj][r] + bvv[nj];
                kvp[nj] = fmaf(kk, vv, kvp[nj]);
                ksp[nj] += kk;
            }
        }
    #pragma unroll
    for (int nj = 0; nj < 2; ++nj) {
        redkv[wm * 4 + quad][wn * 32 + nj * 16 + lr] = kvp[nj];
        redks[wm * 4 + quad][wn * 32 + nj * 16 + lr] = ksp[nj];
    }
    __syncthreads();
    if (t < 64) {
        float s = 0.f;
        #pragma unroll
        for (int g = 0; g < 8; ++g) s += redkv[g][t];
        atomicAdd(&KV[n * 1024 + h0 + t], s);
    } else if (t < 128) {
        const int c = t - 64;
        float s = 0.f;
        #pragma unroll
        for (int g = 0; g < 8; ++g) s += redks[g][c];
        atomicAdd(&Ks[n * 1024 + h0 + c], s);
    }
}

// ---------------------------------------------------------------------------
// V' = Q*KV / (Q*Ksum + 1e-6), elementwise in-place on Q (bf16)
// ---------------------------------------------------------------------------
__global__ __launch_bounds__(256) void vprime(
    unsigned short* __restrict__ Q,
    const float* __restrict__ KV, const float* __restrict__ Ks)
{
    const size_t idx  = (size_t)blockIdx.x * 256 + threadIdx.x;
    const size_t base = idx * 8;
    const int h = (int)(base & 1023);
    const int n = (int)(base >> 23);              // /(8192*1024)
    ushort8 q8 = *(ushort8*)&Q[base];
    const float* kvp = &KV[n * 1024 + h];
    const float* ksp = &Ks[n * 1024 + h];
    ushort8 o;
    #pragma unroll
    for (int j = 0; j < 8; ++j) {
        float qf = bf2f(q8[j]);
        float vp = qf * kvp[j] * __builtin_amdgcn_rcpf(fmaf(qf, ksp[j], 1e-6f));
        o[j] = f2bf(vp);
    }
    *(ushort8*)&Q[base] = o;
}

// ---------------------------------------------------------------------------
// Phase B: out = gelu(V' @ wo + bo).  BM=128, BN=64, BK=64, same wave layout.
// ---------------------------------------------------------------------------
__global__ __launch_bounds__(256) void out_mfma(
    const unsigned short* __restrict__ Vp,
    const unsigned short* __restrict__ woT,
    const float* __restrict__ bo, float* __restrict__ out)
{
    __shared__ unsigned short Alds[128 * 72];
    __shared__ unsigned short Blds[64 * 72];

    const int t  = threadIdx.x;
    const int h0 = blockIdx.x * 64;
    const int m0 = blockIdx.y * 128;

    const int lane = t & 63, wid = t >> 6;
    const int wm = wid >> 1, wn = wid & 1;
    const int lr = lane & 15, quad = lane >> 4;

    const int sr = t >> 2;                 // staging row 0..63
    const int sc = (t & 3) * 16;           // A staging col (16 shorts)

    f32x4 acc[4][2];
    #pragma unroll
    for (int mi = 0; mi < 4; ++mi)
        #pragma unroll
        for (int nj = 0; nj < 2; ++nj) acc[mi][nj] = (f32x4){0.f, 0.f, 0.f, 0.f};

    for (int k0 = 0; k0 < 1024; k0 += 64) {
        ushort8 a0[2], a1[2], b0[2];
        #pragma unroll
        for (int rep = 0; rep < 2; ++rep) {
            a0[rep] = *(const ushort8*)&Vp[(size_t)(m0 + sr + 64 * rep) * 1024 + k0 + sc];
            a1[rep] = *(const ushort8*)&Vp[(size_t)(m0 + sr + 64 * rep) * 1024 + k0 + sc + 8];
            b0[rep] = *(const ushort8*)&woT[(size_t)(h0 + sr) * 1024 + k0 + ((t & 3) + 4 * rep) * 8];
        }
        __syncthreads();
        #pragma unroll
        for (int rep = 0; rep < 2; ++rep) {
            *(ushort8*)&Alds[(sr + 64 * rep) * 72 + sc]     = a0[rep];
            *(ushort8*)&Alds[(sr + 64 * rep) * 72 + sc + 8] = a1[rep];
            *(ushort8*)&Blds[sr * 72 + ((t & 3) + 4 * rep) * 8] = b0[rep];
        }
        __syncthreads();
        #pragma unroll
        for (int ks = 0; ks < 2; ++ks) {
            bf16x8 af[4];
            #pragma unroll
            for (int mi = 0; mi < 4; ++mi)
                af[mi] = __builtin_bit_cast(bf16x8,
                    *(const ushort8*)&Alds[(wm * 64 + mi * 16 + lr) * 72 + ks * 32 + quad * 8]);
            bf16x8 bf_[2];
            #pragma unroll
            for (int nj = 0; nj < 2; ++nj)
                bf_[nj] = __builtin_bit_cast(bf16x8,
                    *(const ushort8*)&Blds[(wn * 32 + nj * 16 + lr) * 72 + ks * 32 + quad * 8]);
            #pragma unroll
            for (int mi = 0; mi < 4; ++mi)
                #pragma unroll
                for (int nj = 0; nj < 2; ++nj)
                    acc[mi][nj] = __builtin_amdgcn_mfma_f32_16x16x32_bf16(af[mi], bf_[nj], acc[mi][nj], 0, 0, 0);
        }
        __syncthreads();
    }

    float bov[2];
    #pragma unroll
    for (int nj = 0; nj < 2; ++nj) bov[nj] = bo[h0 + wn * 32 + nj * 16 + lr];
    #pragma unroll
    for (int mi = 0; mi < 4; ++mi)
        #pragma unroll
        for (int nj = 0; nj < 2; ++nj) {
            const int h = h0 + wn * 32 + nj * 16 + lr;
            #pragma unroll
            for (int r = 0; r < 4; ++r) {
                const int m = m0 + wm * 64 + mi * 16 + quad * 4 + r;
                out[(size_t)m * 1024 + h] = gelu_tanh(acc[mi][nj][r] + bov[nj]);
            }
        }
}

extern "C" void kernel_launch(void* const* d_in, const int* in_sizes, int n_in,
                              void* d_out, int out_size, void* d_ws, size_t ws_size,
                              hipStream_t stream)
{
    const float* x  = (const float*)d_in[0];
    const float* wq = (const float*)d_in[1];
    const float* bq = (const float*)d_in[2];
    const float* wk = (const float*)d_in[3];
    const float* bk = (const float*)d_in[4];
    const float* wv = (const float*)d_in[5];
    const float* bv = (const float*)d_in[6];
    const float* wo = (const float*)d_in[7];
    const float* bo = (const float*)d_in[8];
    float* out = (float*)d_out;

    // ws layout (bytes):
    //   [0, 64M)          Q / V' bf16   (32768 x 1024)
    //   [64M, +2M x4)     wqT, wkT, wvT, woT bf16 (1024 x 1024 each)
    //   then KV fp32 [4,1024], Ks fp32 [4,1024]
    char* wsb = (char*)d_ws;
    unsigned short* Qws = (unsigned short*)wsb;
    unsigned short* wqT = (unsigned short*)(wsb + (size_t)67108864);
    unsigned short* wkT = wqT + 1048576;
    unsigned short* wvT = wkT + 1048576;
    unsigned short* woT = wvT + 1048576;
    float* KV = (float*)(wsb + (size_t)67108864 + 4 * 2097152);
    float* Ks = KV + 4 * 1024;

    hipMemsetAsync(KV, 0, 2 * 4 * 1024 * sizeof(float), stream);

    dim3 tg(16, 16);
    wtrans<<<tg, 256, 0, stream>>>(wq, wqT);
    wtrans<<<tg, 256, 0, stream>>>(wk, wkT);
    wtrans<<<tg, 256, 0, stream>>>(wv, wvT);
    wtrans<<<tg, 256, 0, stream>>>(wo, woT);

    qkv_mfma<<<dim3(16, 256), 256, 0, stream>>>(x, wqT, wkT, wvT, bq, bk, bv, Qws, KV, Ks);
    vprime<<<16384, 256, 0, stream>>>(Qws, KV, Ks);
    out_mfma<<<dim3(16, 256), 256, 0, stream>>>(Qws, woT, bo, out);
}

// Round 4
// 579.563 us; speedup vs baseline: 5.4187x; 1.0965x over previous
//
#include <hip/hip_runtime.h>
#include <math.h>
#include <stdint.h>

// LinearAttention  N=4, S=8192, D_IN=1024, ATTN_DIM=1024, OUT_DIM=1024
// R4: staging rewrite.  x pre-converted to bf16 (once, not 16x); all GEMM
// tiles staged via global_load_lds width=16 (no VALU, no VGPR round-trip);
// XOR-swizzled LDS layout (chunk (r,j) -> slot r*8 + (j^(r&7))) kills the
// 8-way bank conflicts of the padded layout while staying glds-compatible
// (permutation applied on the per-lane GLOBAL address; LDS dest stays
// wave-uniform base + lane*16).
// ws cap: xb half-buffer (32MB) + Q (64MB) + wT (8MB) = 104MB < 128MB proven.

#define S_LEN 8192
#define M_TOT 32768

typedef __attribute__((ext_vector_type(8))) __bf16 bf16x8;
typedef __attribute__((ext_vector_type(8))) unsigned short ushort8;
typedef __attribute__((ext_vector_type(4))) float f32x4;

__device__ __forceinline__ unsigned short f2bf(float f) {
    unsigned int u = __builtin_bit_cast(unsigned int, f);
    unsigned int r = (u + 0x7fffu + ((u >> 16) & 1u)) >> 16;   // RNE
    return (unsigned short)r;
}
__device__ __forceinline__ float bf2f(unsigned short s) {
    unsigned int u = ((unsigned int)s) << 16;
    return __builtin_bit_cast(float, u);
}
__device__ __forceinline__ float elu1(float v) { return v > 0.f ? v + 1.f : __expf(v); }
__device__ __forceinline__ float gelu_tanh(float v) {
    float u = 1.5957691216057308f * (v + 0.044715f * v * v * v);
    float e = __expf(u);
    float th = 1.f - 2.f / (e + 1.f);
    return 0.5f * v * (1.f + th);
}

// async global->LDS, 16B per lane; LDS dest = wave-uniform base + lane*16
__device__ __forceinline__ void glds16(const void* g, void* l) {
    __builtin_amdgcn_global_load_lds(
        (const __attribute__((address_space(1))) unsigned int*)(uintptr_t)g,
        (__attribute__((address_space(3))) unsigned int*)(uintptr_t)l, 16, 0, 0);
}

// ---------------------------------------------------------------------------
// x fp32 -> bf16 (row-major, unchanged layout), one half (16384 rows) per call
// ---------------------------------------------------------------------------
__global__ __launch_bounds__(256) void xconv(const float* __restrict__ x,
                                             unsigned short* __restrict__ xb)
{
    const size_t base = ((size_t)blockIdx.x * 256 + threadIdx.x) * 8;
    float4 a = *(const float4*)&x[base];
    float4 b = *(const float4*)&x[base + 4];
    ushort8 o;
    o[0] = f2bf(a.x); o[1] = f2bf(a.y); o[2] = f2bf(a.z); o[3] = f2bf(a.w);
    o[4] = f2bf(b.x); o[5] = f2bf(b.y); o[6] = f2bf(b.z); o[7] = f2bf(b.w);
    *(ushort8*)&xb[base] = o;
}

// ---------------------------------------------------------------------------
// weight transpose + convert: w[k][n] fp32 (1024x1024) -> wT[n][k] bf16
// ---------------------------------------------------------------------------
__global__ __launch_bounds__(256) void wtrans(const float* __restrict__ w,
                                              unsigned short* __restrict__ wT)
{
    __shared__ float tile[64][65];
    const int t  = threadIdx.x;
    const int n0 = blockIdx.x * 64;
    const int k0 = blockIdx.y * 64;
    const int r  = t >> 2;
    const int c4 = (t & 3) * 16;
    #pragma unroll
    for (int j = 0; j < 4; ++j) {
        float4 v = *(const float4*)&w[(size_t)(k0 + r) * 1024 + n0 + c4 + j * 4];
        tile[r][c4 + j * 4 + 0] = v.x; tile[r][c4 + j * 4 + 1] = v.y;
        tile[r][c4 + j * 4 + 2] = v.z; tile[r][c4 + j * 4 + 3] = v.w;
    }
    __syncthreads();
    const int nn = t >> 2;
    const int kc = (t & 3) * 16;
    ushort8 o0, o1;
    #pragma unroll
    for (int j = 0; j < 8; ++j) o0[j] = f2bf(tile[kc + j][nn]);
    #pragma unroll
    for (int j = 0; j < 8; ++j) o1[j] = f2bf(tile[kc + 8 + j][nn]);
    *(ushort8*)&wT[(size_t)(n0 + nn) * 1024 + k0 + kc]     = o0;
    *(ushort8*)&wT[(size_t)(n0 + nn) * 1024 + k0 + kc + 8] = o1;
}

// ---------------------------------------------------------------------------
// Phase A: fused QKV.  BM=128, BN=64 (per matrix), BK=64, 4 waves (2x2),
// wave tile 64x32 per matrix = 4x2 tiles of 16x16, MFMA 16x16x32 bf16.
// glds staging: A = 16 chunks-instr (4/wave), B = 8/matrix (2/wave).
// ---------------------------------------------------------------------------
__global__ __launch_bounds__(256) void qkv_mfma(
    const unsigned short* __restrict__ xb,       // half: [16384,1024] bf16
    const unsigned short* __restrict__ wqT,
    const unsigned short* __restrict__ wkT,
    const unsigned short* __restrict__ wvT,
    const float* __restrict__ bq, const float* __restrict__ bk,
    const float* __restrict__ bv,
    unsigned short* __restrict__ Qout,           // full [32768,1024]
    float* __restrict__ KV, float* __restrict__ Ks,
    int moff)
{
    __shared__ unsigned short Alds[128 * 64];
    __shared__ unsigned short Blds[3][64 * 64];
    __shared__ float redkv[8][64];
    __shared__ float redks[8][64];

    const int t  = threadIdx.x;
    const int h0 = blockIdx.x * 64;
    const int m0 = blockIdx.y * 128;             // local row base within half
    const int mg = moff + m0;                    // global row base
    const int n  = mg >> 13;

    const int lane = t & 63, wid = t >> 6;
    const int wm = wid >> 1, wn = wid & 1;
    const int lr = lane & 15, quad = lane >> 4;

    f32x4 accq[4][2], acck[4][2], accv[4][2];
    #pragma unroll
    for (int mi = 0; mi < 4; ++mi)
        #pragma unroll
        for (int nj = 0; nj < 2; ++nj) {
            accq[mi][nj] = (f32x4){0.f, 0.f, 0.f, 0.f};
            acck[mi][nj] = (f32x4){0.f, 0.f, 0.f, 0.f};
            accv[mi][nj] = (f32x4){0.f, 0.f, 0.f, 0.f};
        }

    for (int k0 = 0; k0 < 1024; k0 += 64) {
        __syncthreads();                          // prev tile reads complete
        // ---- A stage: slots s=wid*256+i*64+lane; chunk(r,j): r=s>>3, j=(s&7)^(r&7)
        #pragma unroll
        for (int i = 0; i < 4; ++i) {
            const int s = wid * 256 + i * 64 + lane;
            const int r = s >> 3;
            const int j = (s & 7) ^ (r & 7);
            glds16(&xb[(size_t)(m0 + r) * 1024 + k0 + j * 8],
                   &Alds[(wid * 256 + i * 64) * 8]);
        }
        // ---- B stage (3 matrices): slots s=wid*128+i*64+lane over 512
        #pragma unroll
        for (int i = 0; i < 2; ++i) {
            const int s = wid * 128 + i * 64 + lane;
            const int r = s >> 3;
            const int j = (s & 7) ^ (r & 7);
            const size_t go = (size_t)(h0 + r) * 1024 + k0 + j * 8;
            const int lo = (wid * 128 + i * 64) * 8;
            glds16(&wqT[go], &Blds[0][lo]);
            glds16(&wkT[go], &Blds[1][lo]);
            glds16(&wvT[go], &Blds[2][lo]);
        }
        __syncthreads();                          // vmcnt(0) drained by compiler
        // ---- compute: 2 k-steps of 32 ----
        #pragma unroll
        for (int ks = 0; ks < 2; ++ks) {
            bf16x8 af[4];
            #pragma unroll
            for (int mi = 0; mi < 4; ++mi) {
                const int r = wm * 64 + mi * 16 + lr;
                const int off = r * 64 + (((ks * 4 + quad) ^ (r & 7)) * 8);
                af[mi] = __builtin_bit_cast(bf16x8, *(const ushort8*)&Alds[off]);
            }
            bf16x8 bfq[2], bfk[2], bfv[2];
            #pragma unroll
            for (int nj = 0; nj < 2; ++nj) {
                const int r = wn * 32 + nj * 16 + lr;
                const int off = r * 64 + (((ks * 4 + quad) ^ (r & 7)) * 8);
                bfq[nj] = __builtin_bit_cast(bf16x8, *(const ushort8*)&Blds[0][off]);
                bfk[nj] = __builtin_bit_cast(bf16x8, *(const ushort8*)&Blds[1][off]);
                bfv[nj] = __builtin_bit_cast(bf16x8, *(const ushort8*)&Blds[2][off]);
            }
            #pragma unroll
            for (int mi = 0; mi < 4; ++mi)
                #pragma unroll
                for (int nj = 0; nj < 2; ++nj) {
                    accq[mi][nj] = __builtin_amdgcn_mfma_f32_16x16x32_bf16(af[mi], bfq[nj], accq[mi][nj], 0, 0, 0);
                    acck[mi][nj] = __builtin_amdgcn_mfma_f32_16x16x32_bf16(af[mi], bfk[nj], acck[mi][nj], 0, 0, 0);
                    accv[mi][nj] = __builtin_amdgcn_mfma_f32_16x16x32_bf16(af[mi], bfv[nj], accv[mi][nj], 0, 0, 0);
                }
        }
    }

    // ---- epilogue: bias, elu+1, Q store (bf16), KV/Ksum partials ----
    float bqv[2], bkv[2], bvv[2];
    #pragma unroll
    for (int nj = 0; nj < 2; ++nj) {
        const int h = h0 + wn * 32 + nj * 16 + lr;
        bqv[nj] = bq[h]; bkv[nj] = bk[h]; bvv[nj] = bv[h];
    }
    float kvp[2] = {0.f, 0.f}, ksp[2] = {0.f, 0.f};
    #pragma unroll
    for (int mi = 0; mi < 4; ++mi)
        #pragma unroll
        for (int nj = 0; nj < 2; ++nj) {
            const int h = h0 + wn * 32 + nj * 16 + lr;
            #pragma unroll
            for (int r = 0; r < 4; ++r) {
                const int m = mg + wm * 64 + mi * 16 + quad * 4 + r;
                float q = elu1(accq[mi][nj][r] + bqv[nj]);
                Qout[(size_t)m * 1024 + h] = f2bf(q);
                float kk = elu1(acck[mi][nj][r] + bkv[nj]);
                float vv = accv[mi][nj][r] + bvv[nj];
                kvp[nj] = fmaf(kk, vv, kvp[nj]);
                ksp[nj] += kk;
            }
        }
    #pragma unroll
    for (int nj = 0; nj < 2; ++nj) {
        redkv[wm * 4 + quad][wn * 32 + nj * 16 + lr] = kvp[nj];
        redks[wm * 4 + quad][wn * 32 + nj * 16 + lr] = ksp[nj];
    }
    __syncthreads();
    if (t < 64) {
        float s = 0.f;
        #pragma unroll
        for (int g = 0; g < 8; ++g) s += redkv[g][t];
        atomicAdd(&KV[n * 1024 + h0 + t], s);
    } else if (t < 128) {
        const int c = t - 64;
        float s = 0.f;
        #pragma unroll
        for (int g = 0; g < 8; ++g) s += redks[g][c];
        atomicAdd(&Ks[n * 1024 + h0 + c], s);
    }
}

// ---------------------------------------------------------------------------
// V' = Q*KV / (Q*Ksum + 1e-6), elementwise in-place on Q (bf16)
// ---------------------------------------------------------------------------
__global__ __launch_bounds__(256) void vprime(
    unsigned short* __restrict__ Q,
    const float* __restrict__ KV, const float* __restrict__ Ks)
{
    const size_t idx  = (size_t)blockIdx.x * 256 + threadIdx.x;
    const size_t base = idx * 8;
    const int h = (int)(base & 1023);
    const int n = (int)(base >> 23);
    ushort8 q8 = *(ushort8*)&Q[base];
    const float* kvp = &KV[n * 1024 + h];
    const float* ksp = &Ks[n * 1024 + h];
    ushort8 o;
    #pragma unroll
    for (int j = 0; j < 8; ++j) {
        float qf = bf2f(q8[j]);
        float vp = qf * kvp[j] * __builtin_amdgcn_rcpf(fmaf(qf, ksp[j], 1e-6f));
        o[j] = f2bf(vp);
    }
    *(ushort8*)&Q[base] = o;
}

// ---------------------------------------------------------------------------
// Phase B: out = gelu(V' @ wo + bo).  BM=128, BN=64, BK=64, same wave layout,
// glds + swizzle staging.
// ---------------------------------------------------------------------------
__global__ __launch_bounds__(256) void out_mfma(
    const unsigned short* __restrict__ Vp,
    const unsigned short* __restrict__ woT,
    const float* __restrict__ bo, float* __restrict__ out)
{
    __shared__ unsigned short Alds[128 * 64];
    __shared__ unsigned short Blds[64 * 64];

    const int t  = threadIdx.x;
    const int h0 = blockIdx.x * 64;
    const int m0 = blockIdx.y * 128;

    const int lane = t & 63, wid = t >> 6;
    const int wm = wid >> 1, wn = wid & 1;
    const int lr = lane & 15, quad = lane >> 4;

    f32x4 acc[4][2];
    #pragma unroll
    for (int mi = 0; mi < 4; ++mi)
        #pragma unroll
        for (int nj = 0; nj < 2; ++nj) acc[mi][nj] = (f32x4){0.f, 0.f, 0.f, 0.f};

    for (int k0 = 0; k0 < 1024; k0 += 64) {
        __syncthreads();
        #pragma unroll
        for (int i = 0; i < 4; ++i) {
            const int s = wid * 256 + i * 64 + lane;
            const int r = s >> 3;
            const int j = (s & 7) ^ (r & 7);
            glds16(&Vp[(size_t)(m0 + r) * 1024 + k0 + j * 8],
                   &Alds[(wid * 256 + i * 64) * 8]);
        }
        #pragma unroll
        for (int i = 0; i < 2; ++i) {
            const int s = wid * 128 + i * 64 + lane;
            const int r = s >> 3;
            const int j = (s & 7) ^ (r & 7);
            glds16(&woT[(size_t)(h0 + r) * 1024 + k0 + j * 8],
                   &Blds[(wid * 128 + i * 64) * 8]);
        }
        __syncthreads();
        #pragma unroll
        for (int ks = 0; ks < 2; ++ks) {
            bf16x8 af[4];
            #pragma unroll
            for (int mi = 0; mi < 4; ++mi) {
                const int r = wm * 64 + mi * 16 + lr;
                const int off = r * 64 + (((ks * 4 + quad) ^ (r & 7)) * 8);
                af[mi] = __builtin_bit_cast(bf16x8, *(const ushort8*)&Alds[off]);
            }
            bf16x8 bf_[2];
            #pragma unroll
            for (int nj = 0; nj < 2; ++nj) {
                const int r = wn * 32 + nj * 16 + lr;
                const int off = r * 64 + (((ks * 4 + quad) ^ (r & 7)) * 8);
                bf_[nj] = __builtin_bit_cast(bf16x8, *(const ushort8*)&Blds[off]);
            }
            #pragma unroll
            for (int mi = 0; mi < 4; ++mi)
                #pragma unroll
                for (int nj = 0; nj < 2; ++nj)
                    acc[mi][nj] = __builtin_amdgcn_mfma_f32_16x16x32_bf16(af[mi], bf_[nj], acc[mi][nj], 0, 0, 0);
        }
    }

    float bov[2];
    #pragma unroll
    for (int nj = 0; nj < 2; ++nj) bov[nj] = bo[h0 + wn * 32 + nj * 16 + lr];
    #pragma unroll
    for (int mi = 0; mi < 4; ++mi)
        #pragma unroll
        for (int nj = 0; nj < 2; ++nj) {
            const int h = h0 + wn * 32 + nj * 16 + lr;
            #pragma unroll
            for (int r = 0; r < 4; ++r) {
                const int m = m0 + wm * 64 + mi * 16 + quad * 4 + r;
                out[(size_t)m * 1024 + h] = gelu_tanh(acc[mi][nj][r] + bov[nj]);
            }
        }
}

extern "C" void kernel_launch(void* const* d_in, const int* in_sizes, int n_in,
                              void* d_out, int out_size, void* d_ws, size_t ws_size,
                              hipStream_t stream)
{
    const float* x  = (const float*)d_in[0];
    const float* wq = (const float*)d_in[1];
    const float* bq = (const float*)d_in[2];
    const float* wk = (const float*)d_in[3];
    const float* bk = (const float*)d_in[4];
    const float* wv = (const float*)d_in[5];
    const float* bv = (const float*)d_in[6];
    const float* wo = (const float*)d_in[7];
    const float* bo = (const float*)d_in[8];
    float* out = (float*)d_out;

    // ws layout (bytes):
    //   [0, 64M)        Q / V' bf16  (32768 x 1024)
    //   [64M, 96M)      xb bf16 half (16384 x 1024), reused for both halves
    //   [96M, 104M)     wqT, wkT, wvT, woT bf16 (2MB each)
    //   [104M, ...)     KV fp32 [4,1024], Ks fp32 [4,1024]
    char* wsb = (char*)d_ws;
    unsigned short* Qws = (unsigned short*)wsb;
    unsigned short* xb  = (unsigned short*)(wsb + 67108864ULL);
    unsigned short* wqT = (unsigned short*)(wsb + 100663296ULL);
    unsigned short* wkT = wqT + 1048576;
    unsigned short* wvT = wkT + 1048576;
    unsigned short* woT = wvT + 1048576;
    float* KV = (float*)(wsb + 100663296ULL + 4ULL * 2097152);
    float* Ks = KV + 4 * 1024;

    hipMemsetAsync(KV, 0, 2 * 4 * 1024 * sizeof(float), stream);

    dim3 tg(16, 16);
    wtrans<<<tg, 256, 0, stream>>>(wq, wqT);
    wtrans<<<tg, 256, 0, stream>>>(wk, wkT);
    wtrans<<<tg, 256, 0, stream>>>(wv, wvT);
    wtrans<<<tg, 256, 0, stream>>>(wo, woT);

    for (int half = 0; half < 2; ++half) {
        xconv<<<8192, 256, 0, stream>>>(x + (size_t)half * 16384 * 1024, xb);
        qkv_mfma<<<dim3(16, 128), 256, 0, stream>>>(xb, wqT, wkT, wvT, bq, bk, bv,
                                                    Qws, KV, Ks, half * 16384);
    }
    vprime<<<16384, 256, 0, stream>>>(Qws, KV, Ks);
    out_mfma<<<dim3(16, 256), 256, 0, stream>>>(Qws, woT, bo, out);
}